// Round 4
// baseline (1557.482 us; speedup 1.0000x reference)
//
#include <hip/hip_runtime.h>

// WaveNet on gfx950, fp16 MFMA path, round 4.
// r2 skeleton + fixes: layer kernel stages both taps at once into split LDS buffers
// (one barrier), aliases Os onto the dead tap0 buffer -> 52.2 KB LDS -> 3 blocks/CU,
// rcp-based gate computed pre-barrier, register residual-add from LDS R_old,
// coalesced transposed stores (r3's scattered stores caused write-allocate blowup).
// Head reverted to r2 (proven fastest).

#define TT 8192
#define HIDC 128
#define GOODC 2046
#define TGT 6146
#define NL 20

typedef _Float16 half8_t __attribute__((ext_vector_type(8)));
typedef _Float16 half4_t __attribute__((ext_vector_type(4)));
typedef float floatx4 __attribute__((ext_vector_type(4)));

__device__ __forceinline__ floatx4 mfma16(half8_t a, half8_t b, floatx4 c) {
  return __builtin_amdgcn_mfma_f32_16x16x32_f16(a, b, c, 0, 0, 0);
}

__device__ __forceinline__ float fast_sigmoid(float x) {
  return __builtin_amdgcn_rcpf(1.0f + __expf(-x));
}
__device__ __forceinline__ float fast_tanh(float x) {
  return 2.0f * __builtin_amdgcn_rcpf(1.0f + __expf(-2.0f * x)) - 1.0f;
}

// ---------------- weight prep: fp32 -> fp16, stacked layouts ----------------
__global__ void prep_kernel(const float* __restrict__ Wi, const float* __restrict__ Wf,
                            const float* __restrict__ Wg, const float* __restrict__ Wr,
                            const float* __restrict__ W1, const float* __restrict__ W2,
                            _Float16* __restrict__ WIh, _Float16* __restrict__ WFG,
                            _Float16* __restrict__ WRh, _Float16* __restrict__ W1h,
                            _Float16* __restrict__ W2h) {
  int idx = blockIdx.x * blockDim.x + threadIdx.x;
  int stride = gridDim.x * blockDim.x;
  // WFG[l][m][k]: m<128 -> Wf row m, else Wg row m-128; k<128 -> tap0 (u-d), else tap1 (u)
  for (int i = idx; i < NL * 256 * 256; i += stride) {
    int l = i >> 16; int m = (i >> 8) & 255; int k = i & 255;
    int tap = k >> 7; int ci = k & 127;
    float v;
    if (m < 128) v = Wf[(((size_t)l * 128 + m) * 128 + ci) * 2 + tap];
    else         v = Wg[(((size_t)l * 128 + (m - 128)) * 128 + ci) * 2 + tap];
    WFG[i] = (_Float16)v;
  }
  for (int i = idx; i < NL * 128 * 128; i += stride) WRh[i] = (_Float16)Wr[i];
  for (int i = idx; i < 128 * 256; i += stride) WIh[i] = (_Float16)Wi[i];
  for (int i = idx; i < 512 * 128; i += stride) W1h[i] = (_Float16)W1[i];
  for (int i = idx; i < 256 * 512; i += stride) W2h[i] = (_Float16)W2[i];
}

// ---------------- input 1x1 conv: R0[b][u][c] = Wi @ inputs + bi (fp16 out) ----------------
__global__ __launch_bounds__(256, 3) void input_kernel(
    const float* __restrict__ inp, const _Float16* __restrict__ WIh,
    const float* __restrict__ bi, _Float16* __restrict__ R0) {
  __shared__ __align__(16) _Float16 Xs[64][264];
  const int tid = threadIdx.x;
  const int lane = tid & 63;
  const int w = tid >> 6;
  const int ml = lane & 15;
  const int mq = lane >> 4;
  const int b = blockIdx.y;
  const int u0 = blockIdx.x * 64;
  const float* ib = inp + (size_t)b * 256 * TT;

  for (int i = tid; i < 64 * 16; i += 256) {
    int n4 = i & 15;
    int kg = i >> 4;
    const float* src = ib + (size_t)(kg * 4) * TT + u0 + n4 * 4;
    floatx4 c0 = *(const floatx4*)(src);
    floatx4 c1 = *(const floatx4*)(src + TT);
    floatx4 c2 = *(const floatx4*)(src + 2 * TT);
    floatx4 c3 = *(const floatx4*)(src + 3 * TT);
#pragma unroll
    for (int t = 0; t < 4; ++t) {
      half4_t h;
      h[0] = (_Float16)c0[t]; h[1] = (_Float16)c1[t];
      h[2] = (_Float16)c2[t]; h[3] = (_Float16)c3[t];
      *(half4_t*)&Xs[n4 * 4 + t][kg * 4] = h;
    }
  }
  __syncthreads();

  floatx4 acc[2][4];
#pragma unroll
  for (int a = 0; a < 2; ++a)
#pragma unroll
    for (int c = 0; c < 4; ++c) acc[a][c] = floatx4{0.f, 0.f, 0.f, 0.f};

  const _Float16* Aw = WIh + (size_t)(32 * w + ml) * 256;
  for (int kk = 0; kk < 8; ++kk) {
    const int ko = kk * 32 + mq * 8;
    half8_t a0 = *(const half8_t*)(Aw + ko);
    half8_t a1 = *(const half8_t*)(Aw + 16 * 256 + ko);
#pragma unroll
    for (int nt = 0; nt < 4; ++nt) {
      half8_t bv = *(const half8_t*)&Xs[nt * 16 + ml][ko];
      acc[0][nt] = mfma16(a0, bv, acc[0][nt]);
      acc[1][nt] = mfma16(a1, bv, acc[1][nt]);
    }
  }
  __syncthreads();
  float* Xf = (float*)&Xs[0][0];
#pragma unroll
  for (int mt = 0; mt < 2; ++mt) {
    const int mb = 32 * w + mt * 16 + mq * 4;
#pragma unroll
    for (int nt = 0; nt < 4; ++nt)
      *(floatx4*)&Xf[(nt * 16 + ml) * 132 + mb] = acc[mt][nt];
  }
  __syncthreads();
  _Float16* Rb = R0 + (size_t)b * TT * HIDC;
  for (int i = tid; i < 64 * 16; i += 256) {
    int n = i >> 4; int c = i & 15;
    floatx4 x0 = *(const floatx4*)&Xf[n * 132 + c * 8];
    floatx4 x1 = *(const floatx4*)&Xf[n * 132 + c * 8 + 4];
    floatx4 b0 = *(const floatx4*)(bi + c * 8);
    floatx4 b1v = *(const floatx4*)(bi + c * 8 + 4);
    half8_t h;
#pragma unroll
    for (int t = 0; t < 4; ++t) {
      h[t] = (_Float16)(x0[t] + b0[t]);
      h[4 + t] = (_Float16)(x1[t] + b1v[t]);
    }
    *(half8_t*)(Rb + (size_t)(u0 + n) * HIDC + c * 8) = h;
  }
}

// ---------------- one residual layer: N=96, split tap buffers, Os aliased on Xs0 ----------------
__global__ __launch_bounds__(512, 6) void layer_kernel(
    const _Float16* __restrict__ Rin, _Float16* __restrict__ Rout,
    const _Float16* __restrict__ WFG, const _Float16* __restrict__ WR,
    const float* __restrict__ bf, const float* __restrict__ bg,
    const float* __restrict__ br, int d, int ustart) {
  __shared__ __align__(16) _Float16 Xs0[96][136];  // tap0 (u-d); later Os; later x^T
  __shared__ __align__(16) _Float16 Xs1[96][136];  // tap1 (u) = R_old (stable)
  const int tid = threadIdx.x;
  const int lane = tid & 63;
  const int w = tid >> 6;   // 0..7
  const int wm = w & 3;     // m-group
  const int wn = w >> 2;    // n-half (48 rows each)
  const int ml = lane & 15;
  const int mq = lane >> 4;
  const int b = blockIdx.y;
  const int u0 = ustart + blockIdx.x * 96;
  const _Float16* Rb = Rin + (size_t)b * TT * HIDC;
  _Float16* Ro = Rout + (size_t)b * TT * HIDC;

  // ---- stage both taps in one pass (6 x 16B chunks per thread), 1 barrier ----
#pragma unroll
  for (int it = 0; it < 3; ++it) {
    int j = it * 512 + tid;         // [0,1536)
    int n = j >> 4, c = j & 15;
    int ua = min(u0 + n - d, TT - 1);   // tap0; u0+n-d >= ustart-d >= 0
    int ub = min(u0 + n, TT - 1);       // tap1
    *(half8_t*)&Xs0[n][c * 8] = *(const half8_t*)(Rb + (size_t)ua * HIDC + c * 8);
    *(half8_t*)&Xs1[n][c * 8] = *(const half8_t*)(Rb + (size_t)ub * HIDC + c * 8);
  }
  __syncthreads();  // b1

  // ---- GEMM1: [f;g](256 rows) x K=256; wave wm owns f-rows & g-rows [32wm,32wm+32) ----
  floatx4 accF[2][3], accG[2][3];
#pragma unroll
  for (int a = 0; a < 2; ++a)
#pragma unroll
    for (int c = 0; c < 3; ++c) {
      accF[a][c] = floatx4{0.f, 0.f, 0.f, 0.f};
      accG[a][c] = floatx4{0.f, 0.f, 0.f, 0.f};
    }
  const _Float16* Af = WFG + (size_t)(32 * wm + ml) * 256;
  const _Float16* Ag = Af + 128 * 256;
#pragma unroll
  for (int h = 0; h < 2; ++h) {
    const _Float16(*X)[136] = h ? Xs1 : Xs0;
    for (int kk = 0; kk < 4; ++kk) {
      const int ko = kk * 32 + mq * 8;   // [0,128)
      const int kw = h * 128 + ko;       // weight col
      half8_t aF0 = *(const half8_t*)(Af + kw);
      half8_t aF1 = *(const half8_t*)(Af + 16 * 256 + kw);
      half8_t aG0 = *(const half8_t*)(Ag + kw);
      half8_t aG1 = *(const half8_t*)(Ag + 16 * 256 + kw);
#pragma unroll
      for (int nt = 0; nt < 3; ++nt) {
        half8_t bv = *(const half8_t*)&X[wn * 48 + nt * 16 + ml][ko];
        accF[0][nt] = mfma16(aF0, bv, accF[0][nt]);
        accF[1][nt] = mfma16(aF1, bv, accF[1][nt]);
        accG[0][nt] = mfma16(aG0, bv, accG[0][nt]);
        accG[1][nt] = mfma16(aG1, bv, accG[1][nt]);
      }
    }
  }

  // ---- gate in registers BEFORE the barrier (trans-pipe overlaps other waves' MFMA) ----
  half4_t og[2][3];
#pragma unroll
  for (int mt = 0; mt < 2; ++mt) {
    const int mb = 32 * wm + mt * 16 + mq * 4;
    floatx4 bfv = *(const floatx4*)(bf + mb);
    floatx4 bgv = *(const floatx4*)(bg + mb);
#pragma unroll
    for (int nt = 0; nt < 3; ++nt) {
#pragma unroll
      for (int r = 0; r < 4; ++r) {
        float fv = fast_tanh(accF[mt][nt][r] + bfv[r]);
        float gv = fast_sigmoid(accG[mt][nt][r] + bgv[r]);
        og[mt][nt][r] = (_Float16)(fv * gv);
      }
    }
  }
  __syncthreads();  // b2: all Xs0 reads complete -> safe to overwrite as Os

  _Float16(*Os)[136] = Xs0;  // alias
#pragma unroll
  for (int mt = 0; mt < 2; ++mt) {
    const int mb = 32 * wm + mt * 16 + mq * 4;
#pragma unroll
    for (int nt = 0; nt < 3; ++nt)
      *(half4_t*)&Os[wn * 48 + nt * 16 + ml][mb] = og[mt][nt];
  }
  __syncthreads();  // b3: Os visible

  // ---- GEMM2: x = WR(128x128) @ out ----
  floatx4 accX[2][3];
#pragma unroll
  for (int a = 0; a < 2; ++a)
#pragma unroll
    for (int c = 0; c < 3; ++c) accX[a][c] = floatx4{0.f, 0.f, 0.f, 0.f};
  const _Float16* Ar = WR + (size_t)(32 * wm + ml) * 128;
#pragma unroll
  for (int kk = 0; kk < 4; ++kk) {
    const int ko = kk * 32 + mq * 8;
    half8_t a0 = *(const half8_t*)(Ar + ko);
    half8_t a1 = *(const half8_t*)(Ar + 16 * 128 + ko);
#pragma unroll
    for (int nt = 0; nt < 3; ++nt) {
      half8_t bv = *(const half8_t*)&Os[wn * 48 + nt * 16 + ml][ko];
      accX[0][nt] = mfma16(a0, bv, accX[0][nt]);
      accX[1][nt] = mfma16(a1, bv, accX[1][nt]);
    }
  }

  // ---- register epilogue: R_new = x + br + R_old (R_old from Xs1, still valid) ----
  half4_t xo[2][3];
#pragma unroll
  for (int mt = 0; mt < 2; ++mt) {
    const int mb = 32 * wm + mt * 16 + mq * 4;
    floatx4 brv = *(const floatx4*)(br + mb);
#pragma unroll
    for (int nt = 0; nt < 3; ++nt) {
      const int n = wn * 48 + nt * 16 + ml;
      half4_t rold = *(const half4_t*)&Xs1[n][mb];
#pragma unroll
      for (int r = 0; r < 4; ++r)
        xo[mt][nt][r] = (_Float16)(accX[mt][nt][r] + brv[r] + (float)rold[r]);
    }
  }
  __syncthreads();  // b4: all Os reads complete -> safe to overwrite with x^T

#pragma unroll
  for (int mt = 0; mt < 2; ++mt) {
    const int mb = 32 * wm + mt * 16 + mq * 4;
#pragma unroll
    for (int nt = 0; nt < 3; ++nt)
      *(half4_t*)&Os[wn * 48 + nt * 16 + ml][mb] = xo[mt][nt];
  }
  __syncthreads();  // b5

  // ---- coalesced store: 16B/lane, row-contiguous ----
#pragma unroll
  for (int it = 0; it < 3; ++it) {
    int j = it * 512 + tid;
    int n = j >> 4, c = j & 15;
    int u = u0 + n;
    if (u < TT)
      *(half8_t*)(Ro + (size_t)u * HIDC + c * 8) = *(const half8_t*)&Os[n][c * 8];
  }
}

// ---------------- head (r2 version): out = W2 @ relu(W1 @ relu(R20-R0) + b1) + b2 ----------------
__global__ __launch_bounds__(512, 4) void head_kernel(
    const _Float16* __restrict__ Rfin, const _Float16* __restrict__ R0,
    const _Float16* __restrict__ W1h, const _Float16* __restrict__ W2h,
    const float* __restrict__ b1, const float* __restrict__ b2,
    float* __restrict__ out) {
  __shared__ __align__(16) _Float16 Hs[64][136];   // relu(final) [n][c=128]
  __shared__ __align__(16) _Float16 H1s[64][264];  // mid half [n][m=256]
  const int tid = threadIdx.x;
  const int lane = tid & 63;
  const int w = tid >> 6;  // 0..7
  const int ml = lane & 15;
  const int mq = lane >> 4;
  const int b = blockIdx.y;
  const int u0 = GOODC + blockIdx.x * 64;
  const _Float16* Ra = Rfin + (size_t)b * TT * HIDC;
  const _Float16* Rz = R0 + (size_t)b * TT * HIDC;

  for (int i = tid; i < 64 * 16; i += 512) {
    int n = i >> 4; int c = i & 15;
    int u = u0 + n; if (u > TT - 1) u = TT - 1;
    half8_t a = *(const half8_t*)(Ra + (size_t)u * HIDC + c * 8);
    half8_t z = *(const half8_t*)(Rz + (size_t)u * HIDC + c * 8);
    half8_t h;
#pragma unroll
    for (int t = 0; t < 8; ++t) {
      float v = (float)a[t] - (float)z[t];
      h[t] = (_Float16)(v > 0.f ? v : 0.f);
    }
    *(half8_t*)&Hs[n][c * 8] = h;
  }
  __syncthreads();

  floatx4 acc2[2][4];
#pragma unroll
  for (int a = 0; a < 2; ++a)
#pragma unroll
    for (int c = 0; c < 4; ++c) acc2[a][c] = floatx4{0.f, 0.f, 0.f, 0.f};

  for (int p = 0; p < 2; ++p) {
    floatx4 acc1[2][4];
#pragma unroll
    for (int a = 0; a < 2; ++a)
#pragma unroll
      for (int c = 0; c < 4; ++c) acc1[a][c] = floatx4{0.f, 0.f, 0.f, 0.f};
    const _Float16* A1 = W1h + (size_t)(256 * p + 32 * w + ml) * 128;
#pragma unroll
    for (int kk = 0; kk < 4; ++kk) {
      const int ko = kk * 32 + mq * 8;
      half8_t av0 = *(const half8_t*)(A1 + ko);
      half8_t av1 = *(const half8_t*)(A1 + 16 * 128 + ko);
#pragma unroll
      for (int nt = 0; nt < 4; ++nt) {
        half8_t bv = *(const half8_t*)&Hs[nt * 16 + ml][ko];
        acc1[0][nt] = mfma16(av0, bv, acc1[0][nt]);
        acc1[1][nt] = mfma16(av1, bv, acc1[1][nt]);
      }
    }
    __syncthreads();
#pragma unroll
    for (int mt = 0; mt < 2; ++mt) {
      const int mb = 32 * w + mt * 16 + mq * 4;
      floatx4 bv = *(const floatx4*)(b1 + 256 * p + mb);
#pragma unroll
      for (int nt = 0; nt < 4; ++nt) {
        half4_t h;
#pragma unroll
        for (int r = 0; r < 4; ++r) {
          float v = acc1[mt][nt][r] + bv[r];
          h[r] = (_Float16)(v > 0.f ? v : 0.f);
        }
        *(half4_t*)&H1s[nt * 16 + ml][mb] = h;
      }
    }
    __syncthreads();
    const _Float16* A2 = W2h + (size_t)(32 * w + ml) * 512 + p * 256;
    for (int kk = 0; kk < 8; ++kk) {
      const int ko = kk * 32 + mq * 8;
      half8_t av0 = *(const half8_t*)(A2 + ko);
      half8_t av1 = *(const half8_t*)(A2 + 16 * 512 + ko);
#pragma unroll
      for (int nt = 0; nt < 4; ++nt) {
        half8_t bv = *(const half8_t*)&H1s[nt * 16 + ml][ko];
        acc2[0][nt] = mfma16(av0, bv, acc2[0][nt]);
        acc2[1][nt] = mfma16(av1, bv, acc2[1][nt]);
      }
    }
    __syncthreads();
  }

  // fp16 out transpose into H1s, then coalesced stores
#pragma unroll
  for (int mt = 0; mt < 2; ++mt) {
    const int mb = 32 * w + mt * 16 + mq * 4;
    floatx4 bv = *(const floatx4*)(b2 + mb);
#pragma unroll
    for (int nt = 0; nt < 4; ++nt) {
      half4_t h;
#pragma unroll
      for (int r = 0; r < 4; ++r) h[r] = (_Float16)(acc2[mt][nt][r] + bv[r]);
      *(half4_t*)&H1s[nt * 16 + ml][mb] = h;
    }
  }
  __syncthreads();
  for (int i = tid; i < 64 * 32; i += 512) {
    int n = i >> 5; int g = i & 31;
    int u = u0 + n;
    if (u < TT) {
      half8_t v = *(const half8_t*)&H1s[n][g * 8];
      float* dst = out + ((size_t)b * TGT + (u - GOODC)) * 256 + g * 8;
      floatx4 v0, v1;
#pragma unroll
      for (int t = 0; t < 4; ++t) { v0[t] = (float)v[t]; v1[t] = (float)v[4 + t]; }
      *(floatx4*)dst = v0;
      *(floatx4*)(dst + 4) = v1;
    }
  }
}

extern "C" void kernel_launch(void* const* d_in, const int* in_sizes, int n_in,
                              void* d_out, int out_size, void* d_ws, size_t ws_size,
                              hipStream_t stream) {
  const float* inputs = (const float*)d_in[0];
  const float* Wi = (const float*)d_in[1];
  const float* bi = (const float*)d_in[2];
  const float* Wf = (const float*)d_in[3];
  const float* bf = (const float*)d_in[4];
  const float* Wg = (const float*)d_in[5];
  const float* bg = (const float*)d_in[6];
  const float* Wr = (const float*)d_in[7];
  const float* br = (const float*)d_in[8];
  const float* W1 = (const float*)d_in[9];
  const float* b1 = (const float*)d_in[10];
  const float* W2 = (const float*)d_in[11];
  const float* b2 = (const float*)d_in[12];
  float* out = (float*)d_out;

  // workspace layout (~54 MB): three fp16 res buffers + fp16 weights
  char* ws = (char*)d_ws;
  _Float16* R0h = (_Float16*)(ws + 0);
  _Float16* Ph  = (_Float16*)(ws + 16777216);
  _Float16* Qh  = (_Float16*)(ws + 33554432);
  _Float16* WFG = (_Float16*)(ws + 50331648);
  _Float16* WRh = (_Float16*)(ws + 52953088);
  _Float16* WIh = (_Float16*)(ws + 53608448);
  _Float16* W1h = (_Float16*)(ws + 53673984);
  _Float16* W2h = (_Float16*)(ws + 53805056);

  prep_kernel<<<dim3(512), dim3(256), 0, stream>>>(Wi, Wf, Wg, Wr, W1, W2,
                                                   WIh, WFG, WRh, W1h, W2h);
  input_kernel<<<dim3(TT / 64, 8), dim3(256), 0, stream>>>(inputs, WIh, bi, R0h);

  int S = 0;
  for (int l = 0; l < NL; ++l) {
    int d = 1 << (l % 10);
    int ustart = S + d;
    const _Float16* rin = (l == 0) ? R0h : ((l & 1) ? Ph : Qh);
    _Float16* rout = (l & 1) ? Qh : Ph;
    int nblk = (TT - ustart + 95) / 96;
    layer_kernel<<<dim3(nblk, 8), dim3(512), 0, stream>>>(
        rin, rout, WFG + (size_t)l * 65536, WRh + (size_t)l * 16384,
        bf + l * 128, bg + l * 128, br + l * 128, d, ustart);
    S = ustart;
  }
  // after l=19 (odd), final res is in Qh
  head_kernel<<<dim3((TGT + 63) / 64, 8), dim3(512), 0, stream>>>(
      Qh, R0h, W1h, W2h, b1, b2, out);
}

// Round 5
// 802.311 us; speedup vs baseline: 1.9412x; 1.9412x over previous
//
#include <hip/hip_runtime.h>

// WaveNet on gfx950, fp16 MFMA path, round 5.
// r4 structure (single-stage, Os aliased on dead tap0, register gate/residual,
// coalesced transposed stores) but 256-thread blocks with __launch_bounds__(256,3)
// so the VGPR cap (~168) can never force accumulator spills (r4's 512,6 cap=~85
// spilled accF/accG to scratch: 159MB writes/layer, MfmaUtil 4%).
// Head: same 256-thread N=64 treatment, 4 mid-passes, persistent GEMM2 accs.

#define TT 8192
#define HIDC 128
#define GOODC 2046
#define TGT 6146
#define NL 20

typedef _Float16 half8_t __attribute__((ext_vector_type(8)));
typedef _Float16 half4_t __attribute__((ext_vector_type(4)));
typedef float floatx4 __attribute__((ext_vector_type(4)));

__device__ __forceinline__ floatx4 mfma16(half8_t a, half8_t b, floatx4 c) {
  return __builtin_amdgcn_mfma_f32_16x16x32_f16(a, b, c, 0, 0, 0);
}

__device__ __forceinline__ float fast_sigmoid(float x) {
  return __builtin_amdgcn_rcpf(1.0f + __expf(-x));
}
__device__ __forceinline__ float fast_tanh(float x) {
  return 2.0f * __builtin_amdgcn_rcpf(1.0f + __expf(-2.0f * x)) - 1.0f;
}

// ---------------- weight prep: fp32 -> fp16, stacked layouts ----------------
__global__ void prep_kernel(const float* __restrict__ Wi, const float* __restrict__ Wf,
                            const float* __restrict__ Wg, const float* __restrict__ Wr,
                            const float* __restrict__ W1, const float* __restrict__ W2,
                            _Float16* __restrict__ WIh, _Float16* __restrict__ WFG,
                            _Float16* __restrict__ WRh, _Float16* __restrict__ W1h,
                            _Float16* __restrict__ W2h) {
  int idx = blockIdx.x * blockDim.x + threadIdx.x;
  int stride = gridDim.x * blockDim.x;
  // WFG[l][m][k]: m<128 -> Wf row m, else Wg row m-128; k<128 -> tap0 (u-d), else tap1 (u)
  for (int i = idx; i < NL * 256 * 256; i += stride) {
    int l = i >> 16; int m = (i >> 8) & 255; int k = i & 255;
    int tap = k >> 7; int ci = k & 127;
    float v;
    if (m < 128) v = Wf[(((size_t)l * 128 + m) * 128 + ci) * 2 + tap];
    else         v = Wg[(((size_t)l * 128 + (m - 128)) * 128 + ci) * 2 + tap];
    WFG[i] = (_Float16)v;
  }
  for (int i = idx; i < NL * 128 * 128; i += stride) WRh[i] = (_Float16)Wr[i];
  for (int i = idx; i < 128 * 256; i += stride) WIh[i] = (_Float16)Wi[i];
  for (int i = idx; i < 512 * 128; i += stride) W1h[i] = (_Float16)W1[i];
  for (int i = idx; i < 256 * 512; i += stride) W2h[i] = (_Float16)W2[i];
}

// ---------------- input 1x1 conv: R0[b][u][c] = Wi @ inputs + bi (fp16 out) ----------------
__global__ __launch_bounds__(256, 3) void input_kernel(
    const float* __restrict__ inp, const _Float16* __restrict__ WIh,
    const float* __restrict__ bi, _Float16* __restrict__ R0) {
  __shared__ __align__(16) _Float16 Xs[64][264];
  const int tid = threadIdx.x;
  const int lane = tid & 63;
  const int w = tid >> 6;
  const int ml = lane & 15;
  const int mq = lane >> 4;
  const int b = blockIdx.y;
  const int u0 = blockIdx.x * 64;
  const float* ib = inp + (size_t)b * 256 * TT;

  for (int i = tid; i < 64 * 16; i += 256) {
    int n4 = i & 15;
    int kg = i >> 4;
    const float* src = ib + (size_t)(kg * 4) * TT + u0 + n4 * 4;
    floatx4 c0 = *(const floatx4*)(src);
    floatx4 c1 = *(const floatx4*)(src + TT);
    floatx4 c2 = *(const floatx4*)(src + 2 * TT);
    floatx4 c3 = *(const floatx4*)(src + 3 * TT);
#pragma unroll
    for (int t = 0; t < 4; ++t) {
      half4_t h;
      h[0] = (_Float16)c0[t]; h[1] = (_Float16)c1[t];
      h[2] = (_Float16)c2[t]; h[3] = (_Float16)c3[t];
      *(half4_t*)&Xs[n4 * 4 + t][kg * 4] = h;
    }
  }
  __syncthreads();

  floatx4 acc[2][4];
#pragma unroll
  for (int a = 0; a < 2; ++a)
#pragma unroll
    for (int c = 0; c < 4; ++c) acc[a][c] = floatx4{0.f, 0.f, 0.f, 0.f};

  const _Float16* Aw = WIh + (size_t)(32 * w + ml) * 256;
  for (int kk = 0; kk < 8; ++kk) {
    const int ko = kk * 32 + mq * 8;
    half8_t a0 = *(const half8_t*)(Aw + ko);
    half8_t a1 = *(const half8_t*)(Aw + 16 * 256 + ko);
#pragma unroll
    for (int nt = 0; nt < 4; ++nt) {
      half8_t bv = *(const half8_t*)&Xs[nt * 16 + ml][ko];
      acc[0][nt] = mfma16(a0, bv, acc[0][nt]);
      acc[1][nt] = mfma16(a1, bv, acc[1][nt]);
    }
  }
  __syncthreads();
  float* Xf = (float*)&Xs[0][0];
#pragma unroll
  for (int mt = 0; mt < 2; ++mt) {
    const int mb = 32 * w + mt * 16 + mq * 4;
#pragma unroll
    for (int nt = 0; nt < 4; ++nt)
      *(floatx4*)&Xf[(nt * 16 + ml) * 132 + mb] = acc[mt][nt];
  }
  __syncthreads();
  _Float16* Rb = R0 + (size_t)b * TT * HIDC;
  for (int i = tid; i < 64 * 16; i += 256) {
    int n = i >> 4; int c = i & 15;
    floatx4 x0 = *(const floatx4*)&Xf[n * 132 + c * 8];
    floatx4 x1 = *(const floatx4*)&Xf[n * 132 + c * 8 + 4];
    floatx4 b0 = *(const floatx4*)(bi + c * 8);
    floatx4 b1v = *(const floatx4*)(bi + c * 8 + 4);
    half8_t h;
#pragma unroll
    for (int t = 0; t < 4; ++t) {
      h[t] = (_Float16)(x0[t] + b0[t]);
      h[4 + t] = (_Float16)(x1[t] + b1v[t]);
    }
    *(half8_t*)(Rb + (size_t)(u0 + n) * HIDC + c * 8) = h;
  }
}

// ---------------- one residual layer: 256 threads, N=64, split tap buffers ----------------
__global__ __launch_bounds__(256, 3) void layer_kernel(
    const _Float16* __restrict__ Rin, _Float16* __restrict__ Rout,
    const _Float16* __restrict__ WFG, const _Float16* __restrict__ WR,
    const float* __restrict__ bf, const float* __restrict__ bg,
    const float* __restrict__ br, int d, int ustart) {
  __shared__ __align__(16) _Float16 Xs0[64][136];  // tap0 (u-d); later Os; later R_new^T
  __shared__ __align__(16) _Float16 Xs1[64][136];  // tap1 (u) = R_old (stable)
  const int tid = threadIdx.x;
  const int lane = tid & 63;
  const int w = tid >> 6;   // 0..3 : m-group (32 f-rows + 32 g-rows)
  const int ml = lane & 15;
  const int mq = lane >> 4;
  const int b = blockIdx.y;
  const int u0 = ustart + blockIdx.x * 64;
  const _Float16* Rb = Rin + (size_t)b * TT * HIDC;
  _Float16* Ro = Rout + (size_t)b * TT * HIDC;

  // ---- stage both taps (2048 x 16B chunks, 8 per thread), 1 barrier ----
#pragma unroll
  for (int it = 0; it < 8; ++it) {
    int j = it * 256 + tid;          // n(6b) | tap(1b) | c(4b)
    int c = j & 15;
    int tap = (j >> 4) & 1;
    int n = j >> 5;
    int u = min(u0 + n - (tap ? 0 : d), TT - 1);  // >= ustart-d >= 0
    _Float16* dst = tap ? &Xs1[n][c * 8] : &Xs0[n][c * 8];
    *(half8_t*)dst = *(const half8_t*)(Rb + (size_t)u * HIDC + c * 8);
  }
  __syncthreads();  // b1

  // ---- GEMM1: [f;g](256 rows) x K=256; wave w owns f-rows & g-rows [32w,32w+32) ----
  floatx4 accF[2][4], accG[2][4];
#pragma unroll
  for (int a = 0; a < 2; ++a)
#pragma unroll
    for (int c = 0; c < 4; ++c) {
      accF[a][c] = floatx4{0.f, 0.f, 0.f, 0.f};
      accG[a][c] = floatx4{0.f, 0.f, 0.f, 0.f};
    }
  const _Float16* Af = WFG + (size_t)(32 * w + ml) * 256;
  const _Float16* Ag = Af + 128 * 256;
#pragma unroll
  for (int h = 0; h < 2; ++h) {
    const _Float16(*X)[136] = h ? Xs1 : Xs0;
#pragma unroll
    for (int kk = 0; kk < 4; ++kk) {
      const int ko = kk * 32 + mq * 8;   // [0,128) LDS col
      const int kw = h * 128 + ko;       // weight col
      half8_t aF0 = *(const half8_t*)(Af + kw);
      half8_t aF1 = *(const half8_t*)(Af + 16 * 256 + kw);
      half8_t aG0 = *(const half8_t*)(Ag + kw);
      half8_t aG1 = *(const half8_t*)(Ag + 16 * 256 + kw);
#pragma unroll
      for (int nt = 0; nt < 4; ++nt) {
        half8_t bv = *(const half8_t*)&X[nt * 16 + ml][ko];
        accF[0][nt] = mfma16(aF0, bv, accF[0][nt]);
        accF[1][nt] = mfma16(aF1, bv, accF[1][nt]);
        accG[0][nt] = mfma16(aG0, bv, accG[0][nt]);
        accG[1][nt] = mfma16(aG1, bv, accG[1][nt]);
      }
    }
  }

  // ---- gate in registers (trans-pipe overlaps other blocks' MFMA) ----
  half4_t og[2][4];
#pragma unroll
  for (int mt = 0; mt < 2; ++mt) {
    const int mb = 32 * w + mt * 16 + mq * 4;
    floatx4 bfv = *(const floatx4*)(bf + mb);
    floatx4 bgv = *(const floatx4*)(bg + mb);
#pragma unroll
    for (int nt = 0; nt < 4; ++nt) {
#pragma unroll
      for (int r = 0; r < 4; ++r) {
        float fv = fast_tanh(accF[mt][nt][r] + bfv[r]);
        float gv = fast_sigmoid(accG[mt][nt][r] + bgv[r]);
        og[mt][nt][r] = (_Float16)(fv * gv);
      }
    }
  }
  __syncthreads();  // b2: all Xs0 reads complete -> reuse as Os

  _Float16(*Os)[136] = Xs0;
#pragma unroll
  for (int mt = 0; mt < 2; ++mt) {
    const int mb = 32 * w + mt * 16 + mq * 4;
#pragma unroll
    for (int nt = 0; nt < 4; ++nt)
      *(half4_t*)&Os[nt * 16 + ml][mb] = og[mt][nt];
  }
  __syncthreads();  // b3: Os visible

  // ---- GEMM2: x = WR(128x128) @ out ----
  floatx4 accX[2][4];
#pragma unroll
  for (int a = 0; a < 2; ++a)
#pragma unroll
    for (int c = 0; c < 4; ++c) accX[a][c] = floatx4{0.f, 0.f, 0.f, 0.f};
  const _Float16* Ar = WR + (size_t)(32 * w + ml) * 128;
#pragma unroll
  for (int kk = 0; kk < 4; ++kk) {
    const int ko = kk * 32 + mq * 8;
    half8_t a0 = *(const half8_t*)(Ar + ko);
    half8_t a1 = *(const half8_t*)(Ar + 16 * 128 + ko);
#pragma unroll
    for (int nt = 0; nt < 4; ++nt) {
      half8_t bv = *(const half8_t*)&Os[nt * 16 + ml][ko];
      accX[0][nt] = mfma16(a0, bv, accX[0][nt]);
      accX[1][nt] = mfma16(a1, bv, accX[1][nt]);
    }
  }

  // ---- register epilogue: R_new = x + br + R_old (from Xs1) ----
  half4_t xo[2][4];
#pragma unroll
  for (int mt = 0; mt < 2; ++mt) {
    const int mb = 32 * w + mt * 16 + mq * 4;
    floatx4 brv = *(const floatx4*)(br + mb);
#pragma unroll
    for (int nt = 0; nt < 4; ++nt) {
      const int n = nt * 16 + ml;
      half4_t rold = *(const half4_t*)&Xs1[n][mb];
#pragma unroll
      for (int r = 0; r < 4; ++r)
        xo[mt][nt][r] = (_Float16)(accX[mt][nt][r] + brv[r] + (float)rold[r]);
    }
  }
  __syncthreads();  // b4: all Os + Xs1 reads complete

#pragma unroll
  for (int mt = 0; mt < 2; ++mt) {
    const int mb = 32 * w + mt * 16 + mq * 4;
#pragma unroll
    for (int nt = 0; nt < 4; ++nt)
      *(half4_t*)&Os[nt * 16 + ml][mb] = xo[mt][nt];
  }
  __syncthreads();  // b5

  // ---- coalesced store: 16B/lane, row-contiguous ----
#pragma unroll
  for (int it = 0; it < 4; ++it) {
    int j = it * 256 + tid;
    int n = j >> 4, c = j & 15;
    int u = u0 + n;
    if (u < TT)
      *(half8_t*)(Ro + (size_t)u * HIDC + c * 8) = *(const half8_t*)&Os[n][c * 8];
  }
}

// ---------------- head: 256 threads, N=64, 4 mid-passes, persistent accs ----------------
__global__ __launch_bounds__(256, 3) void head_kernel(
    const _Float16* __restrict__ Rfin, const _Float16* __restrict__ R0,
    const _Float16* __restrict__ W1h, const _Float16* __restrict__ W2h,
    const float* __restrict__ b1, const float* __restrict__ b2,
    float* __restrict__ out) {
  __shared__ __align__(16) _Float16 Sh[2 * 64 * 136];  // Hs | H1s; later out^T [64][264]
  _Float16* Hs = Sh;                    // [64][136]
  _Float16* H1s = Sh + 64 * 136;        // [64][136]
  const int tid = threadIdx.x;
  const int lane = tid & 63;
  const int w = tid >> 6;   // 0..3
  const int ml = lane & 15;
  const int mq = lane >> 4;
  const int b = blockIdx.y;
  const int u0 = GOODC + blockIdx.x * 64;
  const _Float16* Ra = Rfin + (size_t)b * TT * HIDC;
  const _Float16* Rz = R0 + (size_t)b * TT * HIDC;

  // stage relu(Rfin - R0)
#pragma unroll
  for (int it = 0; it < 4; ++it) {
    int j = it * 256 + tid;
    int n = j >> 4; int c = j & 15;
    int u = min(u0 + n, TT - 1);
    half8_t a = *(const half8_t*)(Ra + (size_t)u * HIDC + c * 8);
    half8_t z = *(const half8_t*)(Rz + (size_t)u * HIDC + c * 8);
    half8_t h;
#pragma unroll
    for (int t = 0; t < 8; ++t) {
      float v = (float)a[t] - (float)z[t];
      h[t] = (_Float16)(v > 0.f ? v : 0.f);
    }
    *(half8_t*)&Hs[n * 136 + c * 8] = h;
  }
  __syncthreads();

  floatx4 accO[4][4];  // wave w out-rows [64w,64w+64): m = 64w+16mt+4mq+r, n = 16nt+ml
#pragma unroll
  for (int a = 0; a < 4; ++a)
#pragma unroll
    for (int c = 0; c < 4; ++c) accO[a][c] = floatx4{0.f, 0.f, 0.f, 0.f};

  for (int p = 0; p < 4; ++p) {
    // GEMM1: mid rows [128p,128p+128); wave w owns 32 rows
    floatx4 acc1[2][4];
#pragma unroll
    for (int a = 0; a < 2; ++a)
#pragma unroll
      for (int c = 0; c < 4; ++c) acc1[a][c] = floatx4{0.f, 0.f, 0.f, 0.f};
    const _Float16* A1 = W1h + (size_t)(128 * p + 32 * w + ml) * 128;
#pragma unroll
    for (int kk = 0; kk < 4; ++kk) {
      const int ko = kk * 32 + mq * 8;
      half8_t av0 = *(const half8_t*)(A1 + ko);
      half8_t av1 = *(const half8_t*)(A1 + 16 * 128 + ko);
#pragma unroll
      for (int nt = 0; nt < 4; ++nt) {
        half8_t bv = *(const half8_t*)&Hs[(nt * 16 + ml) * 136 + ko];
        acc1[0][nt] = mfma16(av0, bv, acc1[0][nt]);
        acc1[1][nt] = mfma16(av1, bv, acc1[1][nt]);
      }
    }
    __syncthreads();  // previous pass's H1s reads complete
#pragma unroll
    for (int mt = 0; mt < 2; ++mt) {
      const int kc = 32 * w + mt * 16 + mq * 4;
      floatx4 bv = *(const floatx4*)(b1 + 128 * p + kc);
#pragma unroll
      for (int nt = 0; nt < 4; ++nt) {
        half4_t h;
#pragma unroll
        for (int r = 0; r < 4; ++r) {
          float v = acc1[mt][nt][r] + bv[r];
          h[r] = (_Float16)(v > 0.f ? v : 0.f);
        }
        *(half4_t*)&H1s[(nt * 16 + ml) * 136 + kc] = h;
      }
    }
    __syncthreads();
    // GEMM2 accumulate: K = this 128-chunk
    const _Float16* A2 = W2h + (size_t)(64 * w + ml) * 512 + p * 128;
#pragma unroll
    for (int kk = 0; kk < 4; ++kk) {
      const int ko = kk * 32 + mq * 8;
#pragma unroll
      for (int nt = 0; nt < 4; ++nt) {
        half8_t bv = *(const half8_t*)&H1s[(nt * 16 + ml) * 136 + ko];
#pragma unroll
        for (int mt = 0; mt < 4; ++mt) {
          half8_t av = *(const half8_t*)(A2 + (size_t)(mt * 16) * 512 + ko);
          accO[mt][nt] = mfma16(av, bv, accO[mt][nt]);
        }
      }
    }
    __syncthreads();  // H1s reads done before next pass overwrites (and before final alias)
  }

  // out^T through LDS (whole Sh dead now): [64 n][264 halfs], cols = 256 out ch
  _Float16* Ot = Sh;
#pragma unroll
  for (int mt = 0; mt < 4; ++mt) {
    const int m = 64 * w + mt * 16 + mq * 4;
    floatx4 bv = *(const floatx4*)(b2 + m);
#pragma unroll
    for (int nt = 0; nt < 4; ++nt) {
      const int n = nt * 16 + ml;
      half4_t h;
#pragma unroll
      for (int r = 0; r < 4; ++r) h[r] = (_Float16)(accO[mt][nt][r] + bv[r]);
      *(half4_t*)&Ot[n * 264 + m] = h;
    }
  }
  __syncthreads();
  // coalesced fp32 stores: 2048 chunks of 8 ch, 8 per thread
#pragma unroll
  for (int it = 0; it < 8; ++it) {
    int j = it * 256 + tid;
    int n = j >> 5; int g = j & 31;
    int u = u0 + n;
    if (u < TT) {
      half8_t v = *(const half8_t*)&Ot[n * 264 + g * 8];
      float* dst = out + ((size_t)b * TGT + (u - GOODC)) * 256 + g * 8;
      floatx4 v0, v1;
#pragma unroll
      for (int t = 0; t < 4; ++t) { v0[t] = (float)v[t]; v1[t] = (float)v[4 + t]; }
      *(floatx4*)dst = v0;
      *(floatx4*)(dst + 4) = v1;
    }
  }
}

extern "C" void kernel_launch(void* const* d_in, const int* in_sizes, int n_in,
                              void* d_out, int out_size, void* d_ws, size_t ws_size,
                              hipStream_t stream) {
  const float* inputs = (const float*)d_in[0];
  const float* Wi = (const float*)d_in[1];
  const float* bi = (const float*)d_in[2];
  const float* Wf = (const float*)d_in[3];
  const float* bf = (const float*)d_in[4];
  const float* Wg = (const float*)d_in[5];
  const float* bg = (const float*)d_in[6];
  const float* Wr = (const float*)d_in[7];
  const float* br = (const float*)d_in[8];
  const float* W1 = (const float*)d_in[9];
  const float* b1 = (const float*)d_in[10];
  const float* W2 = (const float*)d_in[11];
  const float* b2 = (const float*)d_in[12];
  float* out = (float*)d_out;

  // workspace layout (~54 MB): three fp16 res buffers + fp16 weights
  char* ws = (char*)d_ws;
  _Float16* R0h = (_Float16*)(ws + 0);
  _Float16* Ph  = (_Float16*)(ws + 16777216);
  _Float16* Qh  = (_Float16*)(ws + 33554432);
  _Float16* WFG = (_Float16*)(ws + 50331648);
  _Float16* WRh = (_Float16*)(ws + 52953088);
  _Float16* WIh = (_Float16*)(ws + 53608448);
  _Float16* W1h = (_Float16*)(ws + 53673984);
  _Float16* W2h = (_Float16*)(ws + 53805056);

  prep_kernel<<<dim3(512), dim3(256), 0, stream>>>(Wi, Wf, Wg, Wr, W1, W2,
                                                   WIh, WFG, WRh, W1h, W2h);
  input_kernel<<<dim3(TT / 64, 8), dim3(256), 0, stream>>>(inputs, WIh, bi, R0h);

  int S = 0;
  for (int l = 0; l < NL; ++l) {
    int d = 1 << (l % 10);
    int ustart = S + d;
    const _Float16* rin = (l == 0) ? R0h : ((l & 1) ? Ph : Qh);
    _Float16* rout = (l & 1) ? Qh : Ph;
    int nblk = (TT - ustart + 63) / 64;
    layer_kernel<<<dim3(nblk, 8), dim3(256), 0, stream>>>(
        rin, rout, WFG + (size_t)l * 65536, WRh + (size_t)l * 16384,
        bf + l * 128, bg + l * 128, br + l * 128, d, ustart);
    S = ustart;
  }
  // after l=19 (odd), final res is in Qh
  head_kernel<<<dim3((TGT + 63) / 64, 8), dim3(256), 0, stream>>>(
      Qh, R0h, W1h, W2h, b1, b2, out);
}